// Round 1
// baseline (137.995 us; speedup 1.0000x reference)
//
#include <hip/hip_runtime.h>

#define POOL_H 7
#define POOL_W 7
#define CHANS  256

// ---------------------------------------------------------------------------
// Kernel 1: compute per-ROI pyramid level, then a STABLE counting sort by
// level (matches jnp.argsort(lvl, stable=True)). Writes sorted level + sorted
// normalized box into the workspace.
// Single block of 1024 threads (N = 1000 <= 1024).
// ---------------------------------------------------------------------------
__global__ void __launch_bounds__(1024) level_sort_kernel(
    const float* __restrict__ rois, int N,
    int* __restrict__ sorted_lvl, float4* __restrict__ sorted_box)
{
    __shared__ int hist[16][4];   // [wave][level]

    const int tid  = threadIdx.x;
    const int wave = tid >> 6;
    const int lane = tid & 63;

    int lvl = -1;
    float y1 = 0.f, x1 = 0.f, y2 = 0.f, x2 = 0.f;
    if (tid < N) {
        y1 = rois[tid * 4 + 0];
        x1 = rois[tid * 4 + 1];
        y2 = rois[tid * 4 + 2];
        x2 = rois[tid * 4 + 3];
        float h = y2 - y1;
        float w = x2 - x1;
        // lvl = round(log(sqrt(h*w))/log(2) - 5), clipped to [0,3].
        // rintf = round-nearest-even, matching jnp.round.
        float l = logf(sqrtf(h * w)) / logf(2.0f);
        int li = (int)rintf(l - 5.0f);
        lvl = li < 0 ? 0 : (li > 3 ? 3 : li);
    }

    // Per-wave ballots: stable rank within wave + per-wave per-level counts.
    unsigned long long mask[4];
    #pragma unroll
    for (int l = 0; l < 4; ++l) mask[l] = __ballot(lvl == l);
    if (lane == 0) {
        #pragma unroll
        for (int l = 0; l < 4; ++l) hist[wave][l] = __popcll(mask[l]);
    }
    __syncthreads();

    if (lvl >= 0) {
        // rank among same-level ROIs in earlier lanes of this wave
        int pos = __popcll(mask[lvl] & ((1ull << lane) - 1ull));
        // + same-level counts from earlier waves
        for (int w2 = 0; w2 < wave; ++w2) pos += hist[w2][lvl];
        // + all counts from strictly lower levels (stable counting sort base)
        for (int l = 0; l < lvl; ++l)
            #pragma unroll
            for (int w2 = 0; w2 < 16; ++w2) pos += hist[w2][l];

        sorted_lvl[pos] = lvl;
        const float inv = 1.0f / 1024.0f;   // exact (power of two)
        sorted_box[pos] = make_float4(y1 * inv, x1 * inv, y2 * inv, x2 * inv);
    }
}

// ---------------------------------------------------------------------------
// Kernel 2: one block per sorted ROI. 256 threads = 4 waves; each wave owns
// one (py,px) output position at a time (49 positions, stride 4). Lane l
// handles channels [4l, 4l+4) as float4 -> 16B/lane coalesced access.
// ---------------------------------------------------------------------------
__global__ void __launch_bounds__(256) roi_align_kernel(
    const float* __restrict__ f0, const float* __restrict__ f1,
    const float* __restrict__ f2, const float* __restrict__ f3,
    const int* __restrict__ sorted_lvl, const float4* __restrict__ sorted_box,
    float* __restrict__ out)
{
    const int n    = blockIdx.x;
    const int wave = threadIdx.x >> 6;
    const int lane = threadIdx.x & 63;

    const int lvl = sorted_lvl[n];
    const float4 box = sorted_box[n];

    const float* feat;
    int HW;
    switch (lvl) {
        case 0:  feat = f0; HW = 256; break;
        case 1:  feat = f1; HW = 128; break;
        case 2:  feat = f2; HW = 64;  break;
        default: feat = f3; HW = 32;  break;
    }
    const float Hm1 = (float)(HW - 1);

    // iy = y1*(H-1) + py * (y2-y1)*(H-1)/6   (same for x with W=H)
    const float ybase = box.x * Hm1;
    const float xbase = box.y * Hm1;
    const float ystep = (box.z - box.x) * Hm1 * (1.0f / 6.0f);
    const float xstep = (box.w - box.y) * Hm1 * (1.0f / 6.0f);

    float4* outn = (float4*)(out + (size_t)n * (POOL_H * POOL_W * CHANS));

    for (int p = wave; p < POOL_H * POOL_W; p += 4) {
        const int py = p / POOL_W;
        const int px = p % POOL_W;

        const float iy = ybase + (float)py * ystep;
        const float ix = xbase + (float)px * xstep;

        const float y0f = floorf(iy);
        const float x0f = floorf(ix);
        const float ly = iy - y0f;
        const float lx = ix - x0f;

        int y0  = (int)y0f;
        int x0  = (int)x0f;
        int y1i = y0 + 1;
        int x1i = x0 + 1;
        y0  = min(max(y0, 0), HW - 1);
        y1i = min(max(y1i, 0), HW - 1);
        x0  = min(max(x0, 0), HW - 1);
        x1i = min(max(x1i, 0), HW - 1);

        const bool valid = (iy >= 0.0f) & (iy <= Hm1) & (ix >= 0.0f) & (ix <= Hm1);

        const float4* p00 = (const float4*)(feat + ((size_t)(y0  * HW + x0 )) * CHANS) + lane;
        const float4* p01 = (const float4*)(feat + ((size_t)(y0  * HW + x1i)) * CHANS) + lane;
        const float4* p10 = (const float4*)(feat + ((size_t)(y1i * HW + x0 )) * CHANS) + lane;
        const float4* p11 = (const float4*)(feat + ((size_t)(y1i * HW + x1i)) * CHANS) + lane;

        const float4 f00 = *p00;
        const float4 f01 = *p01;
        const float4 f10 = *p10;
        const float4 f11 = *p11;

        float4 val;
        {
            float tx, bx;
            tx = f00.x + (f01.x - f00.x) * lx;
            bx = f10.x + (f11.x - f10.x) * lx;
            val.x = tx + (bx - tx) * ly;
            tx = f00.y + (f01.y - f00.y) * lx;
            bx = f10.y + (f11.y - f10.y) * lx;
            val.y = tx + (bx - tx) * ly;
            tx = f00.z + (f01.z - f00.z) * lx;
            bx = f10.z + (f11.z - f10.z) * lx;
            val.z = tx + (bx - tx) * ly;
            tx = f00.w + (f01.w - f00.w) * lx;
            bx = f10.w + (f11.w - f10.w) * lx;
            val.w = tx + (bx - tx) * ly;
        }
        if (!valid) { val.x = 0.f; val.y = 0.f; val.z = 0.f; val.w = 0.f; }

        outn[p * 64 + lane] = val;
    }
}

extern "C" void kernel_launch(void* const* d_in, const int* in_sizes, int n_in,
                              void* d_out, int out_size, void* d_ws, size_t ws_size,
                              hipStream_t stream) {
    const float* f0   = (const float*)d_in[0];
    const float* f1   = (const float*)d_in[1];
    const float* f2   = (const float*)d_in[2];
    const float* f3   = (const float*)d_in[3];
    const float* rois = (const float*)d_in[4];
    const int N = in_sizes[4] / 4;

    int*    sorted_lvl = (int*)d_ws;
    float4* sorted_box = (float4*)((char*)d_ws + 4096);
    float*  out        = (float*)d_out;

    hipLaunchKernelGGL(level_sort_kernel, dim3(1), dim3(1024), 0, stream,
                       rois, N, sorted_lvl, sorted_box);
    hipLaunchKernelGGL(roi_align_kernel, dim3(N), dim3(256), 0, stream,
                       f0, f1, f2, f3, sorted_lvl, sorted_box, out);
}

// Round 2
// 132.718 us; speedup vs baseline: 1.0398x; 1.0398x over previous
//
#include <hip/hip_runtime.h>

#define POOL_H 7
#define POOL_W 7
#define CHANS  256

// ---------------------------------------------------------------------------
// Kernel 1: per-ROI pyramid level + STABLE counting sort by level (matches
// jnp.argsort(lvl, stable=True)). Single block, 1024 threads (N=1000).
// Keeps the precise logf path: hardware v_log_f32 risks flipping a ROI at a
// level boundary (O(1) output error); this kernel is ~3 us, not worth it.
// ---------------------------------------------------------------------------
__global__ void __launch_bounds__(1024) level_sort_kernel(
    const float* __restrict__ rois, int N,
    int* __restrict__ sorted_lvl, float4* __restrict__ sorted_box)
{
    __shared__ int hist[16][4];   // [wave][level]

    const int tid  = threadIdx.x;
    const int wave = tid >> 6;
    const int lane = tid & 63;

    int lvl = -1;
    float y1 = 0.f, x1 = 0.f, y2 = 0.f, x2 = 0.f;
    if (tid < N) {
        y1 = rois[tid * 4 + 0];
        x1 = rois[tid * 4 + 1];
        y2 = rois[tid * 4 + 2];
        x2 = rois[tid * 4 + 3];
        float h = y2 - y1;
        float w = x2 - x1;
        // lvl = round(log(sqrt(h*w))/log(2) - 5), clip [0,3]; rintf = RNE.
        float l = logf(sqrtf(h * w)) / logf(2.0f);
        int li = (int)rintf(l - 5.0f);
        lvl = li < 0 ? 0 : (li > 3 ? 3 : li);
    }

    unsigned long long mask[4];
    #pragma unroll
    for (int l = 0; l < 4; ++l) mask[l] = __ballot(lvl == l);
    if (lane == 0) {
        #pragma unroll
        for (int l = 0; l < 4; ++l) hist[wave][l] = __popcll(mask[l]);
    }
    __syncthreads();

    if (lvl >= 0) {
        int pos = __popcll(mask[lvl] & ((1ull << lane) - 1ull));
        for (int w2 = 0; w2 < wave; ++w2) pos += hist[w2][lvl];
        for (int l = 0; l < lvl; ++l)
            #pragma unroll
            for (int w2 = 0; w2 < 16; ++w2) pos += hist[w2][l];

        sorted_lvl[pos] = lvl;
        const float inv = 1.0f / 1024.0f;   // exact (power of two)
        sorted_box[pos] = make_float4(y1 * inv, x1 * inv, y2 * inv, x2 * inv);
    }
}

// ---------------------------------------------------------------------------
// Kernel 2: grid (N, 13) x 256 threads. Each of the 4 waves in a block owns
// EXACTLY ONE (py,px) position: p = blockIdx.y*4 + wave (p < 49). All four
// bilinear-corner loads issue immediately with no serial loop -> 49000
// independent waves of memory-level parallelism. Lane l handles channels
// [4l,4l+4) as float4: 16B/lane coalesced loads and stores.
// ---------------------------------------------------------------------------
__global__ void __launch_bounds__(256) roi_align_kernel(
    const float* __restrict__ f0, const float* __restrict__ f1,
    const float* __restrict__ f2, const float* __restrict__ f3,
    const int* __restrict__ sorted_lvl, const float4* __restrict__ sorted_box,
    float* __restrict__ out)
{
    const int n    = blockIdx.x;
    const int wave = threadIdx.x >> 6;
    const int lane = threadIdx.x & 63;

    const int p = blockIdx.y * 4 + wave;
    if (p >= POOL_H * POOL_W) return;

    const int lvl = sorted_lvl[n];
    const float4 box = sorted_box[n];

    const float* feat;
    int HW;
    switch (lvl) {
        case 0:  feat = f0; HW = 256; break;
        case 1:  feat = f1; HW = 128; break;
        case 2:  feat = f2; HW = 64;  break;
        default: feat = f3; HW = 32;  break;
    }
    const float Hm1 = (float)(HW - 1);

    const int py = p / POOL_W;
    const int px = p % POOL_W;

    // iy = y1*(H-1) + py * (y2-y1)*(H-1)/6   (same for x, W=H)
    const float iy = box.x * Hm1 + (float)py * ((box.z - box.x) * Hm1 * (1.0f / 6.0f));
    const float ix = box.y * Hm1 + (float)px * ((box.w - box.y) * Hm1 * (1.0f / 6.0f));

    const float y0f = floorf(iy);
    const float x0f = floorf(ix);
    const float ly = iy - y0f;
    const float lx = ix - x0f;

    int y0  = (int)y0f;
    int x0  = (int)x0f;
    int y1i = y0 + 1;
    int x1i = x0 + 1;
    y0  = min(max(y0, 0), HW - 1);
    y1i = min(max(y1i, 0), HW - 1);
    x0  = min(max(x0, 0), HW - 1);
    x1i = min(max(x1i, 0), HW - 1);

    const bool valid = (iy >= 0.0f) & (iy <= Hm1) & (ix >= 0.0f) & (ix <= Hm1);

    const float4* p00 = (const float4*)(feat + ((size_t)(y0  * HW + x0 )) * CHANS) + lane;
    const float4* p01 = (const float4*)(feat + ((size_t)(y0  * HW + x1i)) * CHANS) + lane;
    const float4* p10 = (const float4*)(feat + ((size_t)(y1i * HW + x0 )) * CHANS) + lane;
    const float4* p11 = (const float4*)(feat + ((size_t)(y1i * HW + x1i)) * CHANS) + lane;

    const float4 f00 = *p00;
    const float4 f01 = *p01;
    const float4 f10 = *p10;
    const float4 f11 = *p11;

    float4 val;
    {
        float tx, bx;
        tx = f00.x + (f01.x - f00.x) * lx;
        bx = f10.x + (f11.x - f10.x) * lx;
        val.x = tx + (bx - tx) * ly;
        tx = f00.y + (f01.y - f00.y) * lx;
        bx = f10.y + (f11.y - f10.y) * lx;
        val.y = tx + (bx - tx) * ly;
        tx = f00.z + (f01.z - f00.z) * lx;
        bx = f10.z + (f11.z - f10.z) * lx;
        val.z = tx + (bx - tx) * ly;
        tx = f00.w + (f01.w - f00.w) * lx;
        bx = f10.w + (f11.w - f10.w) * lx;
        val.w = tx + (bx - tx) * ly;
    }
    if (!valid) { val.x = 0.f; val.y = 0.f; val.z = 0.f; val.w = 0.f; }

    float4* outn = (float4*)(out + (size_t)n * (POOL_H * POOL_W * CHANS));
    outn[p * 64 + lane] = val;
}

extern "C" void kernel_launch(void* const* d_in, const int* in_sizes, int n_in,
                              void* d_out, int out_size, void* d_ws, size_t ws_size,
                              hipStream_t stream) {
    const float* f0   = (const float*)d_in[0];
    const float* f1   = (const float*)d_in[1];
    const float* f2   = (const float*)d_in[2];
    const float* f3   = (const float*)d_in[3];
    const float* rois = (const float*)d_in[4];
    const int N = in_sizes[4] / 4;

    int*    sorted_lvl = (int*)d_ws;
    float4* sorted_box = (float4*)((char*)d_ws + 4096);
    float*  out        = (float*)d_out;

    hipLaunchKernelGGL(level_sort_kernel, dim3(1), dim3(1024), 0, stream,
                       rois, N, sorted_lvl, sorted_box);

    const int npos_blocks = (POOL_H * POOL_W + 3) / 4;   // 13
    hipLaunchKernelGGL(roi_align_kernel, dim3(N, npos_blocks), dim3(256), 0, stream,
                       f0, f1, f2, f3, sorted_lvl, sorted_box, out);
}